// Round 1
// baseline (1175.131 us; speedup 1.0000x reference)
//
#include <hip/hip_runtime.h>
#include <math.h>

#pragma clang fp contract(off)

#define BB 8
#define AA 9
#define HH 64
#define WW 64
#define NN (HH*WW*AA)      /* 36864 */
#define PRE 6000
#define POST 300
#define SELCAP 8192
#define MASKW 188          /* ceil(6000/32) */

/* ---- workspace layout (bytes) ---- */
#define KEYS_OFF    0ULL
#define KEYS_BYTES  (BB*(size_t)NN*8)            /* 2,359,296 */
#define HIST_OFF    (KEYS_OFF + KEYS_BYTES)
#define HIST_BYTES  (BB*65536ULL*4)              /* 2,097,152 */
#define BINFO_OFF   (HIST_OFF + HIST_BYTES)
#define BINFO_BYTES (BB*2*4ULL)
#define SELCNT_OFF  (BINFO_OFF + BINFO_BYTES)
#define SELCNT_BYTES (BB*4ULL)
#define SELK_OFF    4456576ULL                   /* 8-aligned */
#define SELK_BYTES  (BB*(size_t)SELCAP*8)        /* 524,288 */
#define SELIDX_OFF  (SELK_OFF + SELK_BYTES)
#define SELIDX_BYTES (BB*(size_t)PRE*4)          /* 192,000 */
#define BOXES_OFF   5172864ULL                   /* 16-aligned */

/* 1) transform scores -> sortable keys + 16-bit-prefix histogram */
__global__ void keys_kernel(const float* __restrict__ scores,
                            unsigned long long* __restrict__ keys,
                            unsigned* __restrict__ hist) {
    int t = blockIdx.x * blockDim.x + threadIdx.x;
    if (t >= BB * NN) return;
    int b = t / NN;
    int i = t - b * NN;                 /* i = (h*64+w)*9 + a */
    int a = i % AA;
    int pix = i / AA;
    int wq = pix & 63;
    int hq = pix >> 6;
    float s = scores[((b * (2*AA) + AA + a) * HH + hq) * WW + wq];
    unsigned fb = __float_as_uint(s);
    unsigned u = (fb & 0x80000000u) ? ~fb : (fb | 0x80000000u); /* ascending = float ascending */
    unsigned k = ~u;                                            /* ascending = score descending */
    keys[t] = ((unsigned long long)k << 32) | (unsigned)i;
    atomicAdd(&hist[(b << 16) + (k >> 16)], 1u);
}

/* 2) per-batch scan of 65536 bins: find boundary bin T and count C1 below it */
__global__ __launch_bounds__(1024) void scan_kernel(const unsigned* __restrict__ hist,
                                                    unsigned* __restrict__ binfo) {
    int b = blockIdx.x;
    int tid = threadIdx.x;
    const unsigned* h = hist + ((size_t)b << 16);
    unsigned base = tid * 64;
    unsigned s = 0;
    for (int q = 0; q < 64; ++q) s += h[base + q];
    __shared__ unsigned psum[1024];
    psum[tid] = s;
    __syncthreads();
    for (int off = 1; off < 1024; off <<= 1) {
        unsigned v = (tid >= off) ? psum[tid - off] : 0u;
        __syncthreads();
        psum[tid] += v;
        __syncthreads();
    }
    unsigned incl = psum[tid];
    unsigned excl = incl - s;
    if (excl <= (PRE - 1) && (PRE - 1) < incl) {  /* rank 5999 lives in my chunk */
        unsigned c = excl;
        unsigned T = base;
        for (int q = 0; q < 64; ++q) {
            unsigned hv = h[base + q];
            if ((PRE - 1) < c + hv) { T = base + q; break; }
            c += hv;
        }
        binfo[b * 2 + 0] = T;
        binfo[b * 2 + 1] = c;
    }
}

/* 3) compact all keys with bin <= T (guaranteed superset of top-6000, <= SELCAP) */
__global__ void compact_kernel(const unsigned long long* __restrict__ keys,
                               const unsigned* __restrict__ binfo,
                               unsigned* __restrict__ selcnt,
                               unsigned long long* __restrict__ selk) {
    int t = blockIdx.x * blockDim.x + threadIdx.x;
    if (t >= BB * NN) return;
    int b = t / NN;
    unsigned long long key = keys[t];
    unsigned bin = (unsigned)(key >> 48);
    unsigned T = binfo[b * 2 + 0];
    if (bin <= T) {
        unsigned pos = atomicAdd(&selcnt[b], 1u);
        if (pos < SELCAP) selk[((size_t)b << 13) + pos] = key;
    }
}

/* 4) per-batch bitonic sort of <=8192 keys in LDS; emit top-6000 indices in order */
__global__ __launch_bounds__(1024) void sort_kernel(const unsigned* __restrict__ selcnt,
                                                    const unsigned long long* __restrict__ selk,
                                                    unsigned* __restrict__ selidx) {
    __shared__ unsigned long long sk[SELCAP];
    int b = blockIdx.x;
    int tid = threadIdx.x;
    unsigned cnt = selcnt[b];
    if (cnt > SELCAP) cnt = SELCAP;
    for (int q = tid; q < SELCAP; q += 1024)
        sk[q] = (q < (int)cnt) ? selk[((size_t)b << 13) + q] : 0xFFFFFFFFFFFFFFFFULL;
    __syncthreads();
    for (unsigned k = 2; k <= SELCAP; k <<= 1) {
        for (unsigned j = k >> 1; j > 0; j >>= 1) {
            for (unsigned idx0 = tid; idx0 < SELCAP; idx0 += 1024) {
                unsigned ixj = idx0 ^ j;
                if (ixj > idx0) {
                    unsigned long long va = sk[idx0], vb = sk[ixj];
                    bool up = ((idx0 & k) == 0);
                    if ((va > vb) == up) { sk[idx0] = vb; sk[ixj] = va; }
                }
            }
            __syncthreads();
        }
    }
    for (int q = tid; q < PRE; q += 1024)
        selidx[b * PRE + q] = (unsigned)(sk[q] & 0xFFFFFFFFULL);
}

/* 5) decode + clip only the selected boxes (mirrors reference op order, no FMA) */
__global__ void box_kernel(const unsigned* __restrict__ selidx,
                           const float* __restrict__ deltas,
                           const float* __restrict__ anchors,
                           const int* __restrict__ imw,
                           const int* __restrict__ imh,
                           float4* __restrict__ boxes) {
    int t = blockIdx.x * blockDim.x + threadIdx.x;
    if (t >= BB * PRE) return;
    int b = t / PRE;
    unsigned idx = selidx[t];
    int a = idx % AA;
    int pix = idx / AA;
    int wq = pix & 63;
    int hq = pix >> 6;
    float sx = (float)(wq * 16);
    float sy = (float)(hq * 16);
    float ax1 = anchors[a * 4 + 0] + sx;
    float ay1 = anchors[a * 4 + 1] + sy;
    float ax2 = anchors[a * 4 + 2] + sx;
    float ay2 = anchors[a * 4 + 3] + sy;
    float aw = ax2 - ax1 + 1.0f;
    float ah = ay2 - ay1 + 1.0f;
    float acx = ax1 + 0.5f * aw;
    float acy = ay1 + 0.5f * ah;
    size_t dbase = ((size_t)b * (4*AA) + (size_t)a * 4) * (HH*WW) + (size_t)hq * WW + wq;
    float d0 = deltas[dbase + 0*(HH*WW)];
    float d1 = deltas[dbase + 1*(HH*WW)];
    float d2 = deltas[dbase + 2*(HH*WW)];
    float d3 = deltas[dbase + 3*(HH*WW)];
    float pcx = d0 * aw + acx;
    float pcy = d1 * ah + acy;
    float pw = expf(d2) * aw;
    float ph = expf(d3) * ah;
    float fw = (float)(imw[0] - 1);
    float fh = (float)(imh[0] - 1);
    float x1 = fminf(fmaxf(pcx - 0.5f * pw, 0.0f), fw);
    float y1 = fminf(fmaxf(pcy - 0.5f * ph, 0.0f), fh);
    float x2 = fminf(fmaxf(pcx + 0.5f * pw, 0.0f), fw);
    float y2 = fminf(fmaxf(pcy + 0.5f * ph, 0.0f), fh);
    boxes[t] = make_float4(x1, y1, x2, y2);
}

/* 6) greedy NMS, one block per batch. Boxes/areas in registers (6 per thread),
   keep-bits as LDS bitmask, uniform find-next scan, early exit at 300 kept. */
__global__ __launch_bounds__(1024) void nms_kernel(const float4* __restrict__ boxes,
                                                   float* __restrict__ out) {
    int b = blockIdx.x;
    int tid = threadIdx.x;
    __shared__ unsigned kmask[MASKW];
    float4 bx[6];
    float ar[6];
    for (int q = 0; q < 6; ++q) {
        int j = tid + q * 1024;
        if (j < PRE) {
            bx[q] = boxes[b * PRE + j];
            ar[q] = (bx[q].z - bx[q].x + 1.0f) * (bx[q].w - bx[q].y + 1.0f);
        }
    }
    if (tid < MASKW)
        kmask[tid] = (tid == MASKW - 1) ? ((1u << (PRE - (MASKW - 1) * 32)) - 1u) : 0xFFFFFFFFu;
    __syncthreads();

    int cnt = 0;
    int i = 0;
    for (;;) {
        /* uniform find-next-set >= i (broadcast LDS reads, identical on all threads) */
        int w = i >> 5;
        unsigned m = 0;
        if (w < MASKW) m = kmask[w] & (0xFFFFFFFFu << (i & 31));
        while (m == 0) { ++w; if (w >= MASKW) break; m = kmask[w]; }
        if (m == 0) break;
        i = (w << 5) + (__ffs(m) - 1);

        float4 bi = boxes[b * PRE + i];
        if (tid == 0) {
            float* o = out + ((size_t)b * POST + cnt) * 5;
            o[0] = (float)b; o[1] = bi.x; o[2] = bi.y; o[3] = bi.z; o[4] = bi.w;
        }
        ++cnt;
        if (cnt >= POST) break;

        float ai = (bi.z - bi.x + 1.0f) * (bi.w - bi.y + 1.0f);
        for (int q = 0; q < 6; ++q) {
            int j = tid + q * 1024;
            if (j > i && j < PRE) {
                float xx1 = fmaxf(bi.x, bx[q].x);
                float yy1 = fmaxf(bi.y, bx[q].y);
                float xx2 = fminf(bi.z, bx[q].z);
                float yy2 = fminf(bi.w, bx[q].w);
                float iw = fmaxf(xx2 - xx1 + 1.0f, 0.0f);
                float ih = fmaxf(yy2 - yy1 + 1.0f, 0.0f);
                float inter = iw * ih;
                float iou = inter / (ai + ar[q] - inter);
                if (iou > 0.7f) atomicAnd(&kmask[j >> 5], ~(1u << (j & 31)));
            }
        }
        ++i;
        __syncthreads();
    }
    /* zero-fill rows cnt..299 (out re-poisoned before every call) */
    for (int r = cnt + tid; r < POST; r += 1024) {
        float* o = out + ((size_t)b * POST + r) * 5;
        o[0] = 0.0f; o[1] = 0.0f; o[2] = 0.0f; o[3] = 0.0f; o[4] = 0.0f;
    }
}

extern "C" void kernel_launch(void* const* d_in, const int* in_sizes, int n_in,
                              void* d_out, int out_size, void* d_ws, size_t ws_size,
                              hipStream_t stream) {
    const float* scores  = (const float*)d_in[0];
    const float* deltas  = (const float*)d_in[1];
    const float* anchors = (const float*)d_in[2];
    const int*   imw     = (const int*)d_in[3];
    const int*   imh     = (const int*)d_in[4];
    float* out = (float*)d_out;
    char* ws = (char*)d_ws;

    unsigned long long* keys   = (unsigned long long*)(ws + KEYS_OFF);
    unsigned*           hist   = (unsigned*)(ws + HIST_OFF);
    unsigned*           binfo  = (unsigned*)(ws + BINFO_OFF);
    unsigned*           selcnt = (unsigned*)(ws + SELCNT_OFF);
    unsigned long long* selk   = (unsigned long long*)(ws + SELK_OFF);
    unsigned*           selidx = (unsigned*)(ws + SELIDX_OFF);
    float4*             boxes  = (float4*)(ws + BOXES_OFF);

    /* zero hist + binfo + selcnt (ws is poisoned before every call) */
    hipMemsetAsync(ws + HIST_OFF, 0, HIST_BYTES + BINFO_BYTES + SELCNT_BYTES, stream);

    keys_kernel<<<(BB * NN + 255) / 256, 256, 0, stream>>>(scores, keys, hist);
    scan_kernel<<<BB, 1024, 0, stream>>>(hist, binfo);
    compact_kernel<<<(BB * NN + 255) / 256, 256, 0, stream>>>(keys, binfo, selcnt, selk);
    sort_kernel<<<BB, 1024, 0, stream>>>(selcnt, selk, selidx);
    box_kernel<<<(BB * PRE + 255) / 256, 256, 0, stream>>>(selidx, deltas, anchors, imw, imh, boxes);
    nms_kernel<<<BB, 1024, 0, stream>>>(boxes, out);
}

// Round 2
// 682.218 us; speedup vs baseline: 1.7225x; 1.7225x over previous
//
#include <hip/hip_runtime.h>
#include <math.h>

#pragma clang fp contract(off)

#define BB 8
#define AA 9
#define HH 64
#define WW 64
#define NN (HH*WW*AA)      /* 36864 */
#define PRE 6000
#define POST 300
#define SELCAP 8192
#define MASKW 188          /* ceil(6000/32) */

/* ---- workspace layout (bytes) ---- */
#define KEYS_OFF    0ULL
#define KEYS_BYTES  (BB*(size_t)NN*8)            /* 2,359,296 */
#define HIST_OFF    (KEYS_OFF + KEYS_BYTES)
#define HIST_BYTES  (BB*65536ULL*4)              /* 2,097,152 */
#define BINFO_OFF   (HIST_OFF + HIST_BYTES)
#define BINFO_BYTES (BB*2*4ULL)
#define SELCNT_OFF  (BINFO_OFF + BINFO_BYTES)
#define SELCNT_BYTES (BB*4ULL)
#define SELK_OFF    4456576ULL                   /* 8-aligned */
#define SELK_BYTES  (BB*(size_t)SELCAP*8)        /* 524,288 */
#define SELIDX_OFF  (SELK_OFF + SELK_BYTES)
#define SELIDX_BYTES (BB*(size_t)PRE*4)          /* 192,000 */
#define BOXES_OFF   5172864ULL                   /* 16-aligned */

/* 1) transform scores -> sortable keys + 16-bit-prefix histogram */
__global__ void keys_kernel(const float* __restrict__ scores,
                            unsigned long long* __restrict__ keys,
                            unsigned* __restrict__ hist) {
    int t = blockIdx.x * blockDim.x + threadIdx.x;
    if (t >= BB * NN) return;
    int b = t / NN;
    int i = t - b * NN;                 /* i = (h*64+w)*9 + a */
    int a = i % AA;
    int pix = i / AA;
    int wq = pix & 63;
    int hq = pix >> 6;
    float s = scores[((b * (2*AA) + AA + a) * HH + hq) * WW + wq];
    unsigned fb = __float_as_uint(s);
    unsigned u = (fb & 0x80000000u) ? ~fb : (fb | 0x80000000u); /* ascending = float ascending */
    unsigned k = ~u;                                            /* ascending = score descending */
    keys[t] = ((unsigned long long)k << 32) | (unsigned)i;
    atomicAdd(&hist[(b << 16) + (k >> 16)], 1u);
}

/* 2) per-batch scan of 65536 bins: find boundary bin T and count C1 below it */
__global__ __launch_bounds__(1024) void scan_kernel(const unsigned* __restrict__ hist,
                                                    unsigned* __restrict__ binfo) {
    int b = blockIdx.x;
    int tid = threadIdx.x;
    const unsigned* h = hist + ((size_t)b << 16);
    unsigned base = tid * 64;
    unsigned s = 0;
    for (int q = 0; q < 64; ++q) s += h[base + q];
    __shared__ unsigned psum[1024];
    psum[tid] = s;
    __syncthreads();
    for (int off = 1; off < 1024; off <<= 1) {
        unsigned v = (tid >= off) ? psum[tid - off] : 0u;
        __syncthreads();
        psum[tid] += v;
        __syncthreads();
    }
    unsigned incl = psum[tid];
    unsigned excl = incl - s;
    if (excl <= (PRE - 1) && (PRE - 1) < incl) {  /* rank 5999 lives in my chunk */
        unsigned c = excl;
        unsigned T = base;
        for (int q = 0; q < 64; ++q) {
            unsigned hv = h[base + q];
            if ((PRE - 1) < c + hv) { T = base + q; break; }
            c += hv;
        }
        binfo[b * 2 + 0] = T;
        binfo[b * 2 + 1] = c;
    }
}

/* 3) compact all keys with bin <= T (superset of top-6000, <= SELCAP).
   Wave-aggregated atomics: one atomicAdd per wave (b is wave-uniform since
   NN % 64 == 0), offsets via popcount of lower-lane ballot bits.
   R1 post-mortem: per-thread return-value atomicAdd on 8 addresses serialized
   at ~20 cyc each -> 547 us. This cuts atomic count 65K -> <=4.6K. */
__global__ void compact_kernel(const unsigned long long* __restrict__ keys,
                               const unsigned* __restrict__ binfo,
                               unsigned* __restrict__ selcnt,
                               unsigned long long* __restrict__ selk) {
    int t = blockIdx.x * blockDim.x + threadIdx.x;
    bool valid = (t < BB * NN);
    int b = valid ? (t / NN) : 0;
    unsigned long long key = valid ? keys[t] : 0;
    unsigned bin = (unsigned)(key >> 48);
    unsigned T = binfo[b * 2 + 0];
    bool pred = valid && (bin <= T);

    unsigned long long sel = __ballot(pred);
    if (sel == 0) return;
    int lane = threadIdx.x & 63;
    int leader = __ffsll((long long)sel) - 1;
    unsigned base = 0;
    if (lane == leader) base = atomicAdd(&selcnt[b], (unsigned)__popcll(sel));
    base = __shfl(base, leader);
    if (pred) {
        unsigned pos = base + (unsigned)__popcll(sel & ((1ULL << lane) - 1ULL));
        if (pos < SELCAP) selk[((size_t)b << 13) + pos] = key;
    }
}

/* 4) per-batch bitonic sort of <=8192 keys in LDS; emit top-6000 indices in order */
__global__ __launch_bounds__(1024) void sort_kernel(const unsigned* __restrict__ selcnt,
                                                    const unsigned long long* __restrict__ selk,
                                                    unsigned* __restrict__ selidx) {
    __shared__ unsigned long long sk[SELCAP];
    int b = blockIdx.x;
    int tid = threadIdx.x;
    unsigned cnt = selcnt[b];
    if (cnt > SELCAP) cnt = SELCAP;
    for (int q = tid; q < SELCAP; q += 1024)
        sk[q] = (q < (int)cnt) ? selk[((size_t)b << 13) + q] : 0xFFFFFFFFFFFFFFFFULL;
    __syncthreads();
    for (unsigned k = 2; k <= SELCAP; k <<= 1) {
        for (unsigned j = k >> 1; j > 0; j >>= 1) {
            for (unsigned idx0 = tid; idx0 < SELCAP; idx0 += 1024) {
                unsigned ixj = idx0 ^ j;
                if (ixj > idx0) {
                    unsigned long long va = sk[idx0], vb = sk[ixj];
                    bool up = ((idx0 & k) == 0);
                    if ((va > vb) == up) { sk[idx0] = vb; sk[ixj] = va; }
                }
            }
            __syncthreads();
        }
    }
    for (int q = tid; q < PRE; q += 1024)
        selidx[b * PRE + q] = (unsigned)(sk[q] & 0xFFFFFFFFULL);
}

/* 5) decode + clip only the selected boxes (mirrors reference op order, no FMA) */
__global__ void box_kernel(const unsigned* __restrict__ selidx,
                           const float* __restrict__ deltas,
                           const float* __restrict__ anchors,
                           const int* __restrict__ imw,
                           const int* __restrict__ imh,
                           float4* __restrict__ boxes) {
    int t = blockIdx.x * blockDim.x + threadIdx.x;
    if (t >= BB * PRE) return;
    int b = t / PRE;
    unsigned idx = selidx[t];
    int a = idx % AA;
    int pix = idx / AA;
    int wq = pix & 63;
    int hq = pix >> 6;
    float sx = (float)(wq * 16);
    float sy = (float)(hq * 16);
    float ax1 = anchors[a * 4 + 0] + sx;
    float ay1 = anchors[a * 4 + 1] + sy;
    float ax2 = anchors[a * 4 + 2] + sx;
    float ay2 = anchors[a * 4 + 3] + sy;
    float aw = ax2 - ax1 + 1.0f;
    float ah = ay2 - ay1 + 1.0f;
    float acx = ax1 + 0.5f * aw;
    float acy = ay1 + 0.5f * ah;
    size_t dbase = ((size_t)b * (4*AA) + (size_t)a * 4) * (HH*WW) + (size_t)hq * WW + wq;
    float d0 = deltas[dbase + 0*(HH*WW)];
    float d1 = deltas[dbase + 1*(HH*WW)];
    float d2 = deltas[dbase + 2*(HH*WW)];
    float d3 = deltas[dbase + 3*(HH*WW)];
    float pcx = d0 * aw + acx;
    float pcy = d1 * ah + acy;
    float pw = expf(d2) * aw;
    float ph = expf(d3) * ah;
    float fw = (float)(imw[0] - 1);
    float fh = (float)(imh[0] - 1);
    float x1 = fminf(fmaxf(pcx - 0.5f * pw, 0.0f), fw);
    float y1 = fminf(fmaxf(pcy - 0.5f * ph, 0.0f), fh);
    float x2 = fminf(fmaxf(pcx + 0.5f * pw, 0.0f), fw);
    float y2 = fminf(fmaxf(pcy + 0.5f * ph, 0.0f), fh);
    boxes[t] = make_float4(x1, y1, x2, y2);
}

/* 6) greedy NMS, one block per batch. Boxes/areas in registers (6 per thread),
   keep-bits as LDS bitmask, uniform find-next scan, early exit at 300 kept. */
__global__ __launch_bounds__(1024) void nms_kernel(const float4* __restrict__ boxes,
                                                   float* __restrict__ out) {
    int b = blockIdx.x;
    int tid = threadIdx.x;
    __shared__ unsigned kmask[MASKW];
    float4 bx[6];
    float ar[6];
    for (int q = 0; q < 6; ++q) {
        int j = tid + q * 1024;
        if (j < PRE) {
            bx[q] = boxes[b * PRE + j];
            ar[q] = (bx[q].z - bx[q].x + 1.0f) * (bx[q].w - bx[q].y + 1.0f);
        }
    }
    if (tid < MASKW)
        kmask[tid] = (tid == MASKW - 1) ? ((1u << (PRE - (MASKW - 1) * 32)) - 1u) : 0xFFFFFFFFu;
    __syncthreads();

    int cnt = 0;
    int i = 0;
    for (;;) {
        /* uniform find-next-set >= i (broadcast LDS reads, identical on all threads) */
        int w = i >> 5;
        unsigned m = 0;
        if (w < MASKW) m = kmask[w] & (0xFFFFFFFFu << (i & 31));
        while (m == 0) { ++w; if (w >= MASKW) break; m = kmask[w]; }
        if (m == 0) break;
        i = (w << 5) + (__ffs(m) - 1);

        float4 bi = boxes[b * PRE + i];
        if (tid == 0) {
            float* o = out + ((size_t)b * POST + cnt) * 5;
            o[0] = (float)b; o[1] = bi.x; o[2] = bi.y; o[3] = bi.z; o[4] = bi.w;
        }
        ++cnt;
        if (cnt >= POST) break;

        float ai = (bi.z - bi.x + 1.0f) * (bi.w - bi.y + 1.0f);
        for (int q = 0; q < 6; ++q) {
            int j = tid + q * 1024;
            if (j > i && j < PRE) {
                float xx1 = fmaxf(bi.x, bx[q].x);
                float yy1 = fmaxf(bi.y, bx[q].y);
                float xx2 = fminf(bi.z, bx[q].z);
                float yy2 = fminf(bi.w, bx[q].w);
                float iw = fmaxf(xx2 - xx1 + 1.0f, 0.0f);
                float ih = fmaxf(yy2 - yy1 + 1.0f, 0.0f);
                float inter = iw * ih;
                float iou = inter / (ai + ar[q] - inter);
                if (iou > 0.7f) atomicAnd(&kmask[j >> 5], ~(1u << (j & 31)));
            }
        }
        ++i;
        __syncthreads();
    }
    /* zero-fill rows cnt..299 (out re-poisoned before every call) */
    for (int r = cnt + tid; r < POST; r += 1024) {
        float* o = out + ((size_t)b * POST + r) * 5;
        o[0] = 0.0f; o[1] = 0.0f; o[2] = 0.0f; o[3] = 0.0f; o[4] = 0.0f;
    }
}

extern "C" void kernel_launch(void* const* d_in, const int* in_sizes, int n_in,
                              void* d_out, int out_size, void* d_ws, size_t ws_size,
                              hipStream_t stream) {
    const float* scores  = (const float*)d_in[0];
    const float* deltas  = (const float*)d_in[1];
    const float* anchors = (const float*)d_in[2];
    const int*   imw     = (const int*)d_in[3];
    const int*   imh     = (const int*)d_in[4];
    float* out = (float*)d_out;
    char* ws = (char*)d_ws;

    unsigned long long* keys   = (unsigned long long*)(ws + KEYS_OFF);
    unsigned*           hist   = (unsigned*)(ws + HIST_OFF);
    unsigned*           binfo  = (unsigned*)(ws + BINFO_OFF);
    unsigned*           selcnt = (unsigned*)(ws + SELCNT_OFF);
    unsigned long long* selk   = (unsigned long long*)(ws + SELK_OFF);
    unsigned*           selidx = (unsigned*)(ws + SELIDX_OFF);
    float4*             boxes  = (float4*)(ws + BOXES_OFF);

    /* zero hist + binfo + selcnt (ws is poisoned before every call) */
    hipMemsetAsync(ws + HIST_OFF, 0, HIST_BYTES + BINFO_BYTES + SELCNT_BYTES, stream);

    keys_kernel<<<(BB * NN + 255) / 256, 256, 0, stream>>>(scores, keys, hist);
    scan_kernel<<<BB, 1024, 0, stream>>>(hist, binfo);
    compact_kernel<<<(BB * NN + 255) / 256, 256, 0, stream>>>(keys, binfo, selcnt, selk);
    sort_kernel<<<BB, 1024, 0, stream>>>(selcnt, selk, selidx);
    box_kernel<<<(BB * PRE + 255) / 256, 256, 0, stream>>>(selidx, deltas, anchors, imw, imh, boxes);
    nms_kernel<<<BB, 1024, 0, stream>>>(boxes, out);
}